// Round 1
// baseline (517.167 us; speedup 1.0000x reference)
//
#include <hip/hip_runtime.h>
#include <hip/hip_bf16.h>

typedef unsigned short u16;
typedef __attribute__((ext_vector_type(8))) __bf16 bf16x8;
typedef __attribute__((ext_vector_type(4))) float f32x4;

#define LDS_STRIDE 264   // 256 + 8: breaks 512B-stride bank conflicts, keeps 16B align

__device__ __forceinline__ u16 f2bf(float f) {
    unsigned u = __float_as_uint(f);
    u += 0x7fffu + ((u >> 16) & 1u);   // round-to-nearest-even
    return (u16)(u >> 16);
}

// ---------- kernel 0: W1 [H=4][D=256][K=128] fp32 -> W1T [H][K][D] bf16 ----------
__global__ __launch_bounds__(256) void transpose_w1(const float* __restrict__ W1,
                                                    u16* __restrict__ W1T) {
    int idx = blockIdx.x * 256 + threadIdx.x;      // 131072 total
    int h = idx >> 15;
    int rem = idx & 32767;
    int k = rem >> 8;
    int d = rem & 255;
    float v = W1[((size_t)h * 256 + d) * 128 + k];
    W1T[idx] = f2bf(v);
}

// ---------- kernel 1: scores[N][4] = relu(x*W1+b1)*W2 + b2 via bf16 MFMA ----------
// block = 256 thr (4 waves), node tile 128. D[r][n] = sum_d W1T[r][d]*x[n][d].
// MFMA 16x16x32: A[m=lane&15][k=quad*8+j], B[n=lane&15][k=quad*8+j],
// C/D: col=lane&15 (node), row=quad*4+reg (r).   wave tile: r 64 x n 64 (4x4 frags)
__global__ __launch_bounds__(256, 2) void score_kernel(
        const float* __restrict__ x, const u16* __restrict__ W1T,
        const float* __restrict__ b1, const float* __restrict__ W2,
        const float* __restrict__ b2, float* __restrict__ scores, int N) {
    __shared__ u16 xlds[128 * LDS_STRIDE];
    __shared__ float red[2][128];

    const int t = threadIdx.x;
    const int n0 = blockIdx.x * 128;
    const int valid = min(128, N - n0);

    // stage x tile -> LDS bf16 (coalesced float4 loads)
    for (int i = 0; i < 32; ++i) {
        int f = i * 1024 + t * 4;
        int n = f >> 8;
        int d = f & 255;
        ushort4 o;
        if (n < valid) {
            const float4 v = *reinterpret_cast<const float4*>(x + (size_t)(n0 + n) * 256 + d);
            o.x = f2bf(v.x); o.y = f2bf(v.y); o.z = f2bf(v.z); o.w = f2bf(v.w);
        } else {
            o.x = 0; o.y = 0; o.z = 0; o.w = 0;
        }
        *reinterpret_cast<ushort4*>(&xlds[n * LDS_STRIDE + d]) = o;
    }
    __syncthreads();

    const int wave = t >> 6;
    const int lane = t & 63;
    const int l15 = lane & 15;
    const int quad = lane >> 4;
    const int wr = (wave & 1) * 64;     // r range base for this wave
    const int wn = (wave >> 1) * 64;    // node range base for this wave

    for (int h = 0; h < 4; ++h) {
        f32x4 acc[4][4] = {};
        const u16* A0 = W1T + ((size_t)(h * 128 + wr + l15) * 256 + quad * 8);
        const u16* B0 = xlds + (wn + l15) * LDS_STRIDE + quad * 8;

        for (int ds = 0; ds < 256; ds += 32) {
            bf16x8 a[4], b[4];
#pragma unroll
            for (int rt = 0; rt < 4; ++rt)
                a[rt] = *reinterpret_cast<const bf16x8*>(A0 + rt * (16 * 256) + ds);
#pragma unroll
            for (int nt = 0; nt < 4; ++nt)
                b[nt] = *reinterpret_cast<const bf16x8*>(B0 + nt * (16 * LDS_STRIDE) + ds);
#pragma unroll
            for (int rt = 0; rt < 4; ++rt)
#pragma unroll
                for (int nt = 0; nt < 4; ++nt)
                    acc[rt][nt] = __builtin_amdgcn_mfma_f32_16x16x32_bf16(
                        a[rt], b[nt], acc[rt][nt], 0, 0, 0);
        }

        // epilogue: score partial = sum_r relu(h_r + b1_r) * W2_r  (r within-lane)
        float part[4] = {0.f, 0.f, 0.f, 0.f};
#pragma unroll
        for (int rt = 0; rt < 4; ++rt) {
            int rb = wr + rt * 16 + quad * 4;
            float4 w2v = *reinterpret_cast<const float4*>(W2 + h * 128 + rb);
            float4 b1v = *reinterpret_cast<const float4*>(b1 + h * 128 + rb);
#pragma unroll
            for (int nt = 0; nt < 4; ++nt) {
                f32x4 c = acc[rt][nt];
                part[nt] += fmaxf(c[0] + b1v.x, 0.f) * w2v.x
                          + fmaxf(c[1] + b1v.y, 0.f) * w2v.y
                          + fmaxf(c[2] + b1v.z, 0.f) * w2v.z
                          + fmaxf(c[3] + b1v.w, 0.f) * w2v.w;
            }
        }
#pragma unroll
        for (int nt = 0; nt < 4; ++nt) {
            float p = part[nt];
            p += __shfl_xor(p, 16, 64);   // fold quad bit 0
            p += __shfl_xor(p, 32, 64);   // fold quad bit 1
            if (lane < 16) red[wave & 1][wn + nt * 16 + lane] = p;
        }
        __syncthreads();
        if (t < 128 && t < valid)
            scores[(size_t)(n0 + t) * 4 + h] = red[0][t] + red[1][t] + b2[h];
        __syncthreads();
    }
}

// ---------- kernel 2: per-(graph,head) max and 1/sum(exp) ----------
__device__ __forceinline__ int lower_bound(const int* __restrict__ a, int n, int v) {
    int lo = 0, hi = n;
    while (lo < hi) {
        int mid = (lo + hi) >> 1;
        if (a[mid] < v) lo = mid + 1; else hi = mid;
    }
    return lo;
}

__global__ __launch_bounds__(256) void segstat_kernel(
        const float4* __restrict__ scores4, const int* __restrict__ seg,
        float4* __restrict__ mOut, float4* __restrict__ isOut, int N) {
    __shared__ float4 redm[4];
    __shared__ float4 reds[4];
    const int g = blockIdx.x;
    const int t = threadIdx.x;
    const int start = lower_bound(seg, N, g);
    const int end = lower_bound(seg, N, g + 1);

    float4 mx = make_float4(-3.4e38f, -3.4e38f, -3.4e38f, -3.4e38f);
    for (int i = start + t; i < end; i += 256) {
        float4 s = scores4[i];
        mx.x = fmaxf(mx.x, s.x); mx.y = fmaxf(mx.y, s.y);
        mx.z = fmaxf(mx.z, s.z); mx.w = fmaxf(mx.w, s.w);
    }
#pragma unroll
    for (int off = 1; off < 64; off <<= 1) {
        mx.x = fmaxf(mx.x, __shfl_xor(mx.x, off, 64));
        mx.y = fmaxf(mx.y, __shfl_xor(mx.y, off, 64));
        mx.z = fmaxf(mx.z, __shfl_xor(mx.z, off, 64));
        mx.w = fmaxf(mx.w, __shfl_xor(mx.w, off, 64));
    }
    if ((t & 63) == 0) redm[t >> 6] = mx;
    __syncthreads();
    mx = redm[0];
#pragma unroll
    for (int w = 1; w < 4; ++w) {
        mx.x = fmaxf(mx.x, redm[w].x); mx.y = fmaxf(mx.y, redm[w].y);
        mx.z = fmaxf(mx.z, redm[w].z); mx.w = fmaxf(mx.w, redm[w].w);
    }

    float4 sm = make_float4(0.f, 0.f, 0.f, 0.f);
    for (int i = start + t; i < end; i += 256) {
        float4 s = scores4[i];
        sm.x += expf(s.x - mx.x); sm.y += expf(s.y - mx.y);
        sm.z += expf(s.z - mx.z); sm.w += expf(s.w - mx.w);
    }
#pragma unroll
    for (int off = 1; off < 64; off <<= 1) {
        sm.x += __shfl_xor(sm.x, off, 64);
        sm.y += __shfl_xor(sm.y, off, 64);
        sm.z += __shfl_xor(sm.z, off, 64);
        sm.w += __shfl_xor(sm.w, off, 64);
    }
    if ((t & 63) == 0) reds[t >> 6] = sm;
    __syncthreads();
    if (t == 0) {
        float4 tot = reds[0];
        for (int w = 1; w < 4; ++w) {
            tot.x += reds[w].x; tot.y += reds[w].y;
            tot.z += reds[w].z; tot.w += reds[w].w;
        }
        bool nonempty = end > start;
        float4 m_out = nonempty ? mx : make_float4(0.f, 0.f, 0.f, 0.f);
        float4 is;
        is.x = (nonempty && tot.x > 0.f) ? 1.f / tot.x : 0.f;
        is.y = (nonempty && tot.y > 0.f) ? 1.f / tot.y : 0.f;
        is.z = (nonempty && tot.z > 0.f) ? 1.f / tot.z : 0.f;
        is.w = (nonempty && tot.w > 0.f) ? 1.f / tot.w : 0.f;
        mOut[g] = m_out;
        isOut[g] = is;
    }
}

// ---------- kernel 3: out[g][d] += avg_attn[n] * x[n][d], segment sum ----------
__global__ __launch_bounds__(256) void wsum_kernel(
        const float* __restrict__ x, const float* __restrict__ scores,
        const int* __restrict__ seg, const float* __restrict__ mArr,
        const float* __restrict__ isArr, float* __restrict__ out, int N) {
    __shared__ float wl[256];
    __shared__ int gl[256];
    const int t = threadIdx.x;
    const int n0 = blockIdx.x * 256;

    int g = -1;
    float w = 0.f;
    int n = n0 + t;
    if (n < N) {
        g = seg[n];
        float4 s = *reinterpret_cast<const float4*>(scores + (size_t)n * 4);
        float4 m = *reinterpret_cast<const float4*>(mArr + (size_t)g * 4);
        float4 is = *reinterpret_cast<const float4*>(isArr + (size_t)g * 4);
        w = 0.25f * (expf(s.x - m.x) * is.x + expf(s.y - m.y) * is.y +
                     expf(s.z - m.z) * is.z + expf(s.w - m.w) * is.w);
    }
    gl[t] = g;
    wl[t] = w;
    __syncthreads();

    const int cnt = min(256, N - n0);
    float acc = 0.f;
    int cur = gl[0];
    for (int i = 0; i < cnt; ++i) {
        int gi = gl[i];
        if (gi != cur) {                 // wave-uniform branch
            if (cur >= 0) atomicAdd(&out[(size_t)cur * 256 + t], acc);
            acc = 0.f;
            cur = gi;
        }
        acc += wl[i] * x[(size_t)(n0 + i) * 256 + t];
    }
    if (cur >= 0) atomicAdd(&out[(size_t)cur * 256 + t], acc);
}

extern "C" void kernel_launch(void* const* d_in, const int* in_sizes, int n_in,
                              void* d_out, int out_size, void* d_ws, size_t ws_size,
                              hipStream_t stream) {
    const float* x  = (const float*)d_in[0];
    const int* seg  = (const int*)d_in[1];
    // d_in[2] = num_graphs scalar (G=1024, fixed by problem)
    const float* W1 = (const float*)d_in[3];
    const float* b1 = (const float*)d_in[4];
    const float* W2 = (const float*)d_in[5];
    const float* b2 = (const float*)d_in[6];
    float* out = (float*)d_out;

    const int N = in_sizes[0] / 256;     // 200000
    const int G = 1024;

    char* ws = (char*)d_ws;
    float* scores = (float*)ws;                                  // N*4 fp32 = 3.2 MB
    u16* W1T      = (u16*)(ws + (size_t)N * 16);                 // 131072 u16 = 256 KB
    float* mArr   = (float*)(ws + (size_t)N * 16 + 262144);      // G*4 fp32
    float* isArr  = mArr + (size_t)G * 4;                        // G*4 fp32

    hipMemsetAsync(d_out, 0, (size_t)G * 256 * sizeof(float), stream);
    transpose_w1<<<512, 256, 0, stream>>>(W1, W1T);
    score_kernel<<<(N + 127) / 128, 256, 0, stream>>>(x, W1T, b1, W2, b2, scores, N);
    segstat_kernel<<<G, 256, 0, stream>>>((const float4*)scores, seg,
                                          (float4*)mArr, (float4*)isArr, N);
    wsum_kernel<<<(N + 255) / 256, 256, 0, stream>>>(x, scores, seg, mArr, isArr, out, N);
}

// Round 2
// 515.512 us; speedup vs baseline: 1.0032x; 1.0032x over previous
//
#include <hip/hip_runtime.h>
#include <hip/hip_bf16.h>

typedef unsigned short u16;
typedef __attribute__((ext_vector_type(8))) __bf16 bf16x8;
typedef __attribute__((ext_vector_type(4))) float f32x4;

#define LDS_STRIDE 264   // 256 + 8: breaks 512B-stride bank conflicts, keeps 16B align

__device__ __forceinline__ u16 f2bf(float f) {
    unsigned u = __float_as_uint(f);
    u += 0x7fffu + ((u >> 16) & 1u);   // round-to-nearest-even
    return (u16)(u >> 16);
}

// ---------- kernel 0: W1 [H=4][D=256][K=128] fp32 -> W1T [H][K][D] bf16 ----------
__global__ __launch_bounds__(256) void transpose_w1(const float* __restrict__ W1,
                                                    u16* __restrict__ W1T) {
    int idx = blockIdx.x * 256 + threadIdx.x;      // 131072 total
    int h = idx >> 15;
    int rem = idx & 32767;
    int k = rem >> 8;
    int d = rem & 255;
    float v = W1[((size_t)h * 256 + d) * 128 + k];
    W1T[idx] = f2bf(v);
}

// ---------- kernel 1: scores[N][4] = relu(x*W1+b1)*W2 + b2 via bf16 MFMA ----------
// block = 256 thr (4 waves), node tile 128. D[r][n] = sum_d W1T[r][d]*x[n][d].
// MFMA 16x16x32: C/D: col=lane&15 (node), row=quad*4+reg (r). wave tile r64 x n64.
__global__ __launch_bounds__(256, 2) void score_kernel(
        const float* __restrict__ x, const u16* __restrict__ W1T,
        const float* __restrict__ b1, const float* __restrict__ W2,
        const float* __restrict__ b2, float* __restrict__ scores, int N) {
    __shared__ u16 xlds[128 * LDS_STRIDE];
    __shared__ float red[2][4][128];

    const int t = threadIdx.x;
    const int n0 = blockIdx.x * 128;
    const int valid = min(128, N - n0);

    if (valid == 128) {
        // fast path: software-pipelined staging, 2 batches x 16 float4 in flight
        const float* src = x + (size_t)n0 * 256;
#pragma unroll
        for (int batch = 0; batch < 2; ++batch) {
            float4 v[16];
#pragma unroll
            for (int j = 0; j < 16; ++j) {
                int f = (batch * 16 + j) * 1024 + t * 4;
                v[j] = *reinterpret_cast<const float4*>(src + f);
            }
#pragma unroll
            for (int j = 0; j < 16; ++j) {
                int f = (batch * 16 + j) * 1024 + t * 4;
                int n = f >> 8;
                int d = f & 255;
                ushort4 o;
                o.x = f2bf(v[j].x); o.y = f2bf(v[j].y);
                o.z = f2bf(v[j].z); o.w = f2bf(v[j].w);
                *reinterpret_cast<ushort4*>(&xlds[n * LDS_STRIDE + d]) = o;
            }
        }
    } else {
        // boundary block (rare): predicated scalar path
        for (int i = 0; i < 32; ++i) {
            int f = i * 1024 + t * 4;
            int n = f >> 8;
            int d = f & 255;
            ushort4 o;
            if (n < valid) {
                const float4 v = *reinterpret_cast<const float4*>(x + (size_t)(n0 + n) * 256 + d);
                o.x = f2bf(v.x); o.y = f2bf(v.y); o.z = f2bf(v.z); o.w = f2bf(v.w);
            } else {
                o.x = 0; o.y = 0; o.z = 0; o.w = 0;
            }
            *reinterpret_cast<ushort4*>(&xlds[n * LDS_STRIDE + d]) = o;
        }
    }
    __syncthreads();

    const int wave = t >> 6;
    const int lane = t & 63;
    const int l15 = lane & 15;
    const int quad = lane >> 4;
    const int wr = (wave & 1) * 64;     // r range base for this wave
    const int wn = (wave >> 1) * 64;    // node range base for this wave

    for (int h = 0; h < 4; ++h) {
        f32x4 acc[4][4] = {};
        const u16* A0 = W1T + ((size_t)(h * 128 + wr + l15) * 256 + quad * 8);
        const u16* B0 = xlds + (wn + l15) * LDS_STRIDE + quad * 8;

        // hoist epilogue constants so they're resident before the epilogue
        float4 w2v[4], b1v[4];
#pragma unroll
        for (int rt = 0; rt < 4; ++rt) {
            int rb = wr + rt * 16 + quad * 4;
            w2v[rt] = *reinterpret_cast<const float4*>(W2 + h * 128 + rb);
            b1v[rt] = *reinterpret_cast<const float4*>(b1 + h * 128 + rb);
        }

        // software-pipelined K-loop: prefetch A (global/L2) and B (LDS) one iter ahead
        bf16x8 a[2][4], b[2][4];
#pragma unroll
        for (int rt = 0; rt < 4; ++rt)
            a[0][rt] = *reinterpret_cast<const bf16x8*>(A0 + rt * (16 * 256));
#pragma unroll
        for (int nt = 0; nt < 4; ++nt)
            b[0][nt] = *reinterpret_cast<const bf16x8*>(B0 + nt * (16 * LDS_STRIDE));

#pragma unroll
        for (int it = 0; it < 8; ++it) {
            const int cur = it & 1;
            const int nxt = cur ^ 1;
            if (it < 7) {
                const int ds = (it + 1) * 32;
#pragma unroll
                for (int rt = 0; rt < 4; ++rt)
                    a[nxt][rt] = *reinterpret_cast<const bf16x8*>(A0 + rt * (16 * 256) + ds);
#pragma unroll
                for (int nt = 0; nt < 4; ++nt)
                    b[nxt][nt] = *reinterpret_cast<const bf16x8*>(B0 + nt * (16 * LDS_STRIDE) + ds);
            }
#pragma unroll
            for (int rt = 0; rt < 4; ++rt)
#pragma unroll
                for (int nt = 0; nt < 4; ++nt)
                    acc[rt][nt] = __builtin_amdgcn_mfma_f32_16x16x32_bf16(
                        a[cur][rt], b[cur][nt], acc[rt][nt], 0, 0, 0);
        }

        // epilogue: score partial = sum_r relu(h_r + b1_r) * W2_r  (r within-lane)
        float part[4] = {0.f, 0.f, 0.f, 0.f};
#pragma unroll
        for (int rt = 0; rt < 4; ++rt) {
#pragma unroll
            for (int nt = 0; nt < 4; ++nt) {
                f32x4 c = acc[rt][nt];
                part[nt] += fmaxf(c[0] + b1v[rt].x, 0.f) * w2v[rt].x
                          + fmaxf(c[1] + b1v[rt].y, 0.f) * w2v[rt].y
                          + fmaxf(c[2] + b1v[rt].z, 0.f) * w2v[rt].z
                          + fmaxf(c[3] + b1v[rt].w, 0.f) * w2v[rt].w;
            }
        }
#pragma unroll
        for (int nt = 0; nt < 4; ++nt) {
            float p = part[nt];
            p += __shfl_xor(p, 16, 64);   // fold quad bit 0
            p += __shfl_xor(p, 32, 64);   // fold quad bit 1
            if (lane < 16) red[wave & 1][h][wn + nt * 16 + lane] = p;
        }
        // no per-head syncthreads: each (wave, head) writes a disjoint red region
    }
    __syncthreads();
    if (t < 128 && t < valid) {
        float4 s;
        s.x = red[0][0][t] + red[1][0][t] + b2[0];
        s.y = red[0][1][t] + red[1][1][t] + b2[1];
        s.z = red[0][2][t] + red[1][2][t] + b2[2];
        s.w = red[0][3][t] + red[1][3][t] + b2[3];
        *reinterpret_cast<float4*>(scores + (size_t)(n0 + t) * 4) = s;
    }
}

// ---------- kernel 2: per-(graph,head) max and 1/sum(exp) ----------
__device__ __forceinline__ int lower_bound(const int* __restrict__ a, int n, int v) {
    int lo = 0, hi = n;
    while (lo < hi) {
        int mid = (lo + hi) >> 1;
        if (a[mid] < v) lo = mid + 1; else hi = mid;
    }
    return lo;
}

__global__ __launch_bounds__(256) void segstat_kernel(
        const float4* __restrict__ scores4, const int* __restrict__ seg,
        float4* __restrict__ mOut, float4* __restrict__ isOut, int N) {
    __shared__ float4 redm[4];
    __shared__ float4 reds[4];
    const int g = blockIdx.x;
    const int t = threadIdx.x;
    const int start = lower_bound(seg, N, g);
    const int end = lower_bound(seg, N, g + 1);

    float4 mx = make_float4(-3.4e38f, -3.4e38f, -3.4e38f, -3.4e38f);
    for (int i = start + t; i < end; i += 256) {
        float4 s = scores4[i];
        mx.x = fmaxf(mx.x, s.x); mx.y = fmaxf(mx.y, s.y);
        mx.z = fmaxf(mx.z, s.z); mx.w = fmaxf(mx.w, s.w);
    }
#pragma unroll
    for (int off = 1; off < 64; off <<= 1) {
        mx.x = fmaxf(mx.x, __shfl_xor(mx.x, off, 64));
        mx.y = fmaxf(mx.y, __shfl_xor(mx.y, off, 64));
        mx.z = fmaxf(mx.z, __shfl_xor(mx.z, off, 64));
        mx.w = fmaxf(mx.w, __shfl_xor(mx.w, off, 64));
    }
    if ((t & 63) == 0) redm[t >> 6] = mx;
    __syncthreads();
    mx = redm[0];
#pragma unroll
    for (int w = 1; w < 4; ++w) {
        mx.x = fmaxf(mx.x, redm[w].x); mx.y = fmaxf(mx.y, redm[w].y);
        mx.z = fmaxf(mx.z, redm[w].z); mx.w = fmaxf(mx.w, redm[w].w);
    }

    float4 sm = make_float4(0.f, 0.f, 0.f, 0.f);
    for (int i = start + t; i < end; i += 256) {
        float4 s = scores4[i];
        sm.x += expf(s.x - mx.x); sm.y += expf(s.y - mx.y);
        sm.z += expf(s.z - mx.z); sm.w += expf(s.w - mx.w);
    }
#pragma unroll
    for (int off = 1; off < 64; off <<= 1) {
        sm.x += __shfl_xor(sm.x, off, 64);
        sm.y += __shfl_xor(sm.y, off, 64);
        sm.z += __shfl_xor(sm.z, off, 64);
        sm.w += __shfl_xor(sm.w, off, 64);
    }
    if ((t & 63) == 0) reds[t >> 6] = sm;
    __syncthreads();
    if (t == 0) {
        float4 tot = reds[0];
        for (int w = 1; w < 4; ++w) {
            tot.x += reds[w].x; tot.y += reds[w].y;
            tot.z += reds[w].z; tot.w += reds[w].w;
        }
        bool nonempty = end > start;
        float4 m_out = nonempty ? mx : make_float4(0.f, 0.f, 0.f, 0.f);
        float4 is;
        is.x = (nonempty && tot.x > 0.f) ? 1.f / tot.x : 0.f;
        is.y = (nonempty && tot.y > 0.f) ? 1.f / tot.y : 0.f;
        is.z = (nonempty && tot.z > 0.f) ? 1.f / tot.z : 0.f;
        is.w = (nonempty && tot.w > 0.f) ? 1.f / tot.w : 0.f;
        mOut[g] = m_out;
        isOut[g] = is;
    }
}

// ---------- kernel 3: out[g][d] += avg_attn[n] * x[n][d], segment sum ----------
__global__ __launch_bounds__(256) void wsum_kernel(
        const float* __restrict__ x, const float* __restrict__ scores,
        const int* __restrict__ seg, const float* __restrict__ mArr,
        const float* __restrict__ isArr, float* __restrict__ out, int N) {
    __shared__ float wl[256];
    __shared__ int gl[256];
    const int t = threadIdx.x;
    const int n0 = blockIdx.x * 256;

    int g = -1;
    float w = 0.f;
    int n = n0 + t;
    if (n < N) {
        g = seg[n];
        float4 s = *reinterpret_cast<const float4*>(scores + (size_t)n * 4);
        float4 m = *reinterpret_cast<const float4*>(mArr + (size_t)g * 4);
        float4 is = *reinterpret_cast<const float4*>(isArr + (size_t)g * 4);
        w = 0.25f * (expf(s.x - m.x) * is.x + expf(s.y - m.y) * is.y +
                     expf(s.z - m.z) * is.z + expf(s.w - m.w) * is.w);
    }
    gl[t] = g;
    wl[t] = w;
    __syncthreads();

    const int cnt = min(256, N - n0);
    float acc = 0.f;
    int cur = gl[0];
    for (int i = 0; i < cnt; ++i) {
        int gi = gl[i];
        if (gi != cur) {                 // wave-uniform branch
            if (cur >= 0) atomicAdd(&out[(size_t)cur * 256 + t], acc);
            acc = 0.f;
            cur = gi;
        }
        acc += wl[i] * x[(size_t)(n0 + i) * 256 + t];
    }
    if (cur >= 0) atomicAdd(&out[(size_t)cur * 256 + t], acc);
}

extern "C" void kernel_launch(void* const* d_in, const int* in_sizes, int n_in,
                              void* d_out, int out_size, void* d_ws, size_t ws_size,
                              hipStream_t stream) {
    const float* x  = (const float*)d_in[0];
    const int* seg  = (const int*)d_in[1];
    // d_in[2] = num_graphs scalar (G=1024, fixed by problem)
    const float* W1 = (const float*)d_in[3];
    const float* b1 = (const float*)d_in[4];
    const float* W2 = (const float*)d_in[5];
    const float* b2 = (const float*)d_in[6];
    float* out = (float*)d_out;

    const int N = in_sizes[0] / 256;     // 200000
    const int G = 1024;

    char* ws = (char*)d_ws;
    float* scores = (float*)ws;                                  // N*4 fp32 = 3.2 MB
    u16* W1T      = (u16*)(ws + (size_t)N * 16);                 // 131072 u16 = 256 KB
    float* mArr   = (float*)(ws + (size_t)N * 16 + 262144);      // G*4 fp32
    float* isArr  = mArr + (size_t)G * 4;                        // G*4 fp32

    hipMemsetAsync(d_out, 0, (size_t)G * 256 * sizeof(float), stream);
    transpose_w1<<<512, 256, 0, stream>>>(W1, W1T);
    score_kernel<<<(N + 127) / 128, 256, 0, stream>>>(x, W1T, b1, W2, b2, scores, N);
    segstat_kernel<<<G, 256, 0, stream>>>((const float4*)scores, seg,
                                          (float4*)mArr, (float4*)isArr, N);
    wsum_kernel<<<(N + 255) / 256, 256, 0, stream>>>(x, scores, seg, mArr, isArr, out, N);
}

// Round 3
// 420.062 us; speedup vs baseline: 1.2312x; 1.2272x over previous
//
#include <hip/hip_runtime.h>
#include <hip/hip_bf16.h>

typedef unsigned short u16;
typedef __attribute__((ext_vector_type(8))) __bf16 bf16x8;
typedef __attribute__((ext_vector_type(4))) float f32x4;

#define LDS_STRIDE 264   // 256+8: 528B row stride -> conflict-free ds_read_b128

__device__ __forceinline__ u16 f2bf(float f) {
    unsigned u = __float_as_uint(f);
    u += 0x7fffu + ((u >> 16) & 1u);   // round-to-nearest-even
    return (u16)(u >> 16);
}

// ---------- kernel 0: W1 [H=4][D=256][K=128] fp32 -> W1T [H][K][D] bf16 ----------
__global__ __launch_bounds__(256) void transpose_w1(const float* __restrict__ W1,
                                                    u16* __restrict__ W1T) {
    int idx = blockIdx.x * 256 + threadIdx.x;      // 131072 total
    int h = idx >> 15;
    int rem = idx & 32767;
    int k = rem >> 8;
    int d = rem & 255;
    float v = W1[((size_t)h * 256 + d) * 128 + k];
    W1T[idx] = f2bf(v);
}

// ---------- kernel 1: scores[N][4] = relu(x*W1+b1)*W2 + b2 via bf16 MFMA ----------
// 64-node tile, 512 thr = 8 waves. wave w -> head w>>1, r-half (w&1)*64.
// MFMA 16x16x32: C/D col=lane&15 (node), row=quad*4+reg (r).
__global__ __launch_bounds__(512, 4) void score_kernel(
        const float* __restrict__ x, const u16* __restrict__ W1T,
        const float* __restrict__ b1, const float* __restrict__ W2,
        const float* __restrict__ b2, float* __restrict__ scores, int N) {
    __shared__ u16 xlds[64 * LDS_STRIDE];
    __shared__ float red[8][64];

    const int t = threadIdx.x;
    const int n0 = blockIdx.x * 64;
    const int valid = min(64, N - n0);

    // stage 64 x-rows (64 KB fp32 -> 32 KB bf16); 8 float4 per thread
    if (valid == 64) {
        const float* src = x + (size_t)n0 * 256;
        float4 v[8];
#pragma unroll
        for (int i = 0; i < 8; ++i)
            v[i] = *reinterpret_cast<const float4*>(src + i * 2048 + t * 4);
#pragma unroll
        for (int i = 0; i < 8; ++i) {
            int f = i * 2048 + t * 4;
            int n = f >> 8, d = f & 255;
            ushort4 o;
            o.x = f2bf(v[i].x); o.y = f2bf(v[i].y);
            o.z = f2bf(v[i].z); o.w = f2bf(v[i].w);
            *reinterpret_cast<ushort4*>(&xlds[n * LDS_STRIDE + d]) = o;
        }
    } else {
        for (int i = 0; i < 8; ++i) {
            int f = i * 2048 + t * 4;
            int n = f >> 8, d = f & 255;
            ushort4 o; o.x = 0; o.y = 0; o.z = 0; o.w = 0;
            if (n < valid) {
                float4 v = *reinterpret_cast<const float4*>(x + (size_t)(n0 + n) * 256 + d);
                o.x = f2bf(v.x); o.y = f2bf(v.y); o.z = f2bf(v.z); o.w = f2bf(v.w);
            }
            *reinterpret_cast<ushort4*>(&xlds[n * LDS_STRIDE + d]) = o;
        }
    }
    __syncthreads();

    const int wave = t >> 6;
    const int lane = t & 63;
    const int l15 = lane & 15;
    const int quad = lane >> 4;
    const int h = wave >> 1;
    const int wr = (wave & 1) * 64;

    f32x4 acc[4][4] = {};
    const u16* A0 = W1T + ((size_t)(h * 128 + wr + l15) * 256 + quad * 8);
    const u16* B0 = xlds + l15 * LDS_STRIDE + quad * 8;

#pragma unroll
    for (int it = 0; it < 8; ++it) {
        const int ds = it * 32;
        bf16x8 a[4], b[4];
#pragma unroll
        for (int rt = 0; rt < 4; ++rt)
            a[rt] = *reinterpret_cast<const bf16x8*>(A0 + rt * (16 * 256) + ds);
#pragma unroll
        for (int nt = 0; nt < 4; ++nt)
            b[nt] = *reinterpret_cast<const bf16x8*>(B0 + nt * (16 * LDS_STRIDE) + ds);
#pragma unroll
        for (int rt = 0; rt < 4; ++rt)
#pragma unroll
            for (int nt = 0; nt < 4; ++nt)
                acc[rt][nt] = __builtin_amdgcn_mfma_f32_16x16x32_bf16(
                    a[rt], b[nt], acc[rt][nt], 0, 0, 0);
    }

    // epilogue: part[nt] = sum_r relu(acc + b1) * W2  (r lives within lane+reg)
    float part[4] = {0.f, 0.f, 0.f, 0.f};
#pragma unroll
    for (int rt = 0; rt < 4; ++rt) {
        int rb = wr + rt * 16 + quad * 4;
        float4 w2v = *reinterpret_cast<const float4*>(W2 + h * 128 + rb);
        float4 b1v = *reinterpret_cast<const float4*>(b1 + h * 128 + rb);
#pragma unroll
        for (int nt = 0; nt < 4; ++nt) {
            f32x4 c = acc[rt][nt];
            part[nt] += fmaxf(c[0] + b1v.x, 0.f) * w2v.x
                      + fmaxf(c[1] + b1v.y, 0.f) * w2v.y
                      + fmaxf(c[2] + b1v.z, 0.f) * w2v.z
                      + fmaxf(c[3] + b1v.w, 0.f) * w2v.w;
        }
    }
#pragma unroll
    for (int nt = 0; nt < 4; ++nt) {
        float p = part[nt];
        p += __shfl_xor(p, 16, 64);
        p += __shfl_xor(p, 32, 64);
        if (lane < 16) red[wave][nt * 16 + lane] = p;
    }
    __syncthreads();
    if (t < valid) {
        float4 s;
        s.x = red[0][t] + red[1][t] + b2[0];
        s.y = red[2][t] + red[3][t] + b2[1];
        s.z = red[4][t] + red[5][t] + b2[2];
        s.w = red[6][t] + red[7][t] + b2[3];
        *reinterpret_cast<float4*>(scores + (size_t)(n0 + t) * 4) = s;
    }
}

// ---------- kernel 2: fused segment softmax-stats + weighted segment sum ----------
// one block per graph; thread t owns output column d=t; no atomics.
__device__ __forceinline__ int lower_bound(const int* __restrict__ a, int n, int v) {
    int lo = 0, hi = n;
    while (lo < hi) {
        int mid = (lo + hi) >> 1;
        if (a[mid] < v) lo = mid + 1; else hi = mid;
    }
    return lo;
}

__global__ __launch_bounds__(256) void pool_kernel(
        const float* __restrict__ x, const float4* __restrict__ scores4,
        const int* __restrict__ seg, float* __restrict__ out, int N) {
    __shared__ float4 redm[4];
    __shared__ float4 reds[4];
    __shared__ float wlds[64];
    const int g = blockIdx.x;
    const int t = threadIdx.x;
    const int start = lower_bound(seg, N, g);
    const int end = lower_bound(seg, N, g + 1);

    // --- per-head max over segment ---
    float4 mx = make_float4(-3.4e38f, -3.4e38f, -3.4e38f, -3.4e38f);
    for (int i = start + t; i < end; i += 256) {
        float4 s = scores4[i];
        mx.x = fmaxf(mx.x, s.x); mx.y = fmaxf(mx.y, s.y);
        mx.z = fmaxf(mx.z, s.z); mx.w = fmaxf(mx.w, s.w);
    }
#pragma unroll
    for (int off = 1; off < 64; off <<= 1) {
        mx.x = fmaxf(mx.x, __shfl_xor(mx.x, off, 64));
        mx.y = fmaxf(mx.y, __shfl_xor(mx.y, off, 64));
        mx.z = fmaxf(mx.z, __shfl_xor(mx.z, off, 64));
        mx.w = fmaxf(mx.w, __shfl_xor(mx.w, off, 64));
    }
    if ((t & 63) == 0) redm[t >> 6] = mx;
    __syncthreads();
    mx = redm[0];
#pragma unroll
    for (int w = 1; w < 4; ++w) {
        mx.x = fmaxf(mx.x, redm[w].x); mx.y = fmaxf(mx.y, redm[w].y);
        mx.z = fmaxf(mx.z, redm[w].z); mx.w = fmaxf(mx.w, redm[w].w);
    }

    // --- per-head 1/sum(exp) ---
    float4 sm = make_float4(0.f, 0.f, 0.f, 0.f);
    for (int i = start + t; i < end; i += 256) {
        float4 s = scores4[i];
        sm.x += expf(s.x - mx.x); sm.y += expf(s.y - mx.y);
        sm.z += expf(s.z - mx.z); sm.w += expf(s.w - mx.w);
    }
#pragma unroll
    for (int off = 1; off < 64; off <<= 1) {
        sm.x += __shfl_xor(sm.x, off, 64);
        sm.y += __shfl_xor(sm.y, off, 64);
        sm.z += __shfl_xor(sm.z, off, 64);
        sm.w += __shfl_xor(sm.w, off, 64);
    }
    if ((t & 63) == 0) reds[t >> 6] = sm;
    __syncthreads();
    float4 tot = reds[0];
#pragma unroll
    for (int w = 1; w < 4; ++w) {
        tot.x += reds[w].x; tot.y += reds[w].y;
        tot.z += reds[w].z; tot.w += reds[w].w;
    }
    float4 is;
    is.x = tot.x > 0.f ? 1.f / tot.x : 0.f;
    is.y = tot.y > 0.f ? 1.f / tot.y : 0.f;
    is.z = tot.z > 0.f ? 1.f / tot.z : 0.f;
    is.w = tot.w > 0.f ? 1.f / tot.w : 0.f;

    // --- weighted sum: thread t owns column d=t; 64-node chunks ---
    float acc = 0.f;
    for (int base = start; base < end; base += 64) {
        const int cnt = min(64, end - base);
        __syncthreads();
        if (t < 64) {
            float wv = 0.f;
            if (t < cnt) {
                float4 s = scores4[base + t];
                wv = 0.25f * (expf(s.x - mx.x) * is.x + expf(s.y - mx.y) * is.y +
                              expf(s.z - mx.z) * is.z + expf(s.w - mx.w) * is.w);
            }
            wlds[t] = wv;
        }
        __syncthreads();
#pragma unroll
        for (int i = 0; i < 64; i += 8) {
            float xv[8], wv[8];
#pragma unroll
            for (int j = 0; j < 8; ++j) {
                int nidx = base + i + j;
                nidx = nidx < end ? nidx : (N - 1);   // clamp; wv=0 past cnt
                xv[j] = x[(size_t)nidx * 256 + t];
                wv[j] = wlds[i + j];
            }
#pragma unroll
            for (int j = 0; j < 8; ++j) acc += wv[j] * xv[j];
        }
    }
    out[(size_t)g * 256 + t] = acc;   // every graph written, incl. empty -> 0
}

extern "C" void kernel_launch(void* const* d_in, const int* in_sizes, int n_in,
                              void* d_out, int out_size, void* d_ws, size_t ws_size,
                              hipStream_t stream) {
    const float* x  = (const float*)d_in[0];
    const int* seg  = (const int*)d_in[1];
    // d_in[2] = num_graphs scalar (G=1024, fixed by problem)
    const float* W1 = (const float*)d_in[3];
    const float* b1 = (const float*)d_in[4];
    const float* W2 = (const float*)d_in[5];
    const float* b2 = (const float*)d_in[6];
    float* out = (float*)d_out;

    const int N = in_sizes[0] / 256;     // 200000
    const int G = 1024;

    char* ws = (char*)d_ws;
    float* scores = (float*)ws;                                  // N*4 fp32 = 3.2 MB
    u16* W1T      = (u16*)(ws + (size_t)N * 16);                 // 131072 u16 = 256 KB

    transpose_w1<<<512, 256, 0, stream>>>(W1, W1T);
    score_kernel<<<(N + 63) / 64, 512, 0, stream>>>(x, W1T, b1, W2, b2, scores, N);
    pool_kernel<<<G, 256, 0, stream>>>(x, (const float4*)scores, seg, out, N);
}